// Round 2
// baseline (1396.594 us; speedup 1.0000x reference)
//
#include <hip/hip_runtime.h>
#include <cstdint>
#include <cstddef>

typedef __bf16 bf16_t;
typedef bf16_t bf16x8 __attribute__((ext_vector_type(8)));
typedef float floatx4 __attribute__((ext_vector_type(4)));

#define B_   128
#define T_   64
#define H_   512
#define IN_  2048
#define FS_  1536
#define M_   (B_ * T_)   // 8192
#define GB_  64          // persistent-kernel grid blocks

// ---------------------------------------------------------------------------
// async global->LDS, 16B per lane. LDS dest is wave-uniform base + lane*16.
// ---------------------------------------------------------------------------
__device__ __forceinline__ void async16(void* lds, const void* gp) {
  __builtin_amdgcn_global_load_lds(
      (const __attribute__((address_space(1))) void*)gp,
      (__attribute__((address_space(3))) void*)lds, 16, 0, 0);
}

// ---------------------------------------------------------------------------
// fp32 -> bf16 conversion, 8 elems/thread
// ---------------------------------------------------------------------------
__global__ __launch_bounds__(256) void cvt_bf16_k(const float* __restrict__ s,
                                                  bf16_t* __restrict__ d, int n8) {
  int i = blockIdx.x * 256 + threadIdx.x;
  if (i >= n8) return;
  const float4* s4 = (const float4*)s;
  float4 v0 = s4[2 * (size_t)i];
  float4 v1 = s4[2 * (size_t)i + 1];
  bf16x8 o;
  o[0] = (bf16_t)v0.x; o[1] = (bf16_t)v0.y; o[2] = (bf16_t)v0.z; o[3] = (bf16_t)v0.w;
  o[4] = (bf16_t)v1.x; o[5] = (bf16_t)v1.y; o[6] = (bf16_t)v1.z; o[7] = (bf16_t)v1.w;
  *(bf16x8*)(d + (size_t)i * 8) = o;
}

// ---------------------------------------------------------------------------
// C[M,N] = A[M,K] * B[N,K]^T + bias[N]   (bf16 in, fp32 out) — m97 structure
// ---------------------------------------------------------------------------
#define BM 128
#define BN 128
#define BK 32

__global__ __launch_bounds__(256) void gemm_bt_bias(
    const bf16_t* __restrict__ A, const bf16_t* __restrict__ B,
    const float* __restrict__ bias, float* __restrict__ C,
    int M, int N, int K) {
  __shared__ __align__(16) bf16_t As[BM * BK];
  __shared__ __align__(16) bf16_t Bs[BN * BK];

  const int tid  = threadIdx.x;
  const int lane = tid & 63;
  const int wave = tid >> 6;
  const int wr = wave >> 1, wc = wave & 1;
  const int mblk = blockIdx.y * BM;
  const int nblk = blockIdx.x * BN;

  const int sr = lane >> 2;
  const int sc = (lane & 3) * 8;
  const int c0 = wave * 2;

  const bf16_t* Ag0 = A + (size_t)(mblk + c0 * 16 + sr) * K + sc;
  const bf16_t* Ag1 = A + (size_t)(mblk + c0 * 16 + 16 + sr) * K + sc;
  const bf16_t* Bg0 = B + (size_t)(nblk + c0 * 16 + sr) * K + sc;
  const bf16_t* Bg1 = B + (size_t)(nblk + c0 * 16 + 16 + sr) * K + sc;
  bf16_t* As0 = As + c0 * 512;
  bf16_t* Bs0 = Bs + c0 * 512;

  floatx4 acc[4][4] = {};

  const int fm = lane & 15;
  const int fk = (lane >> 4) * 8;

  for (int kt = 0; kt < K; kt += BK) {
    async16(As0,       Ag0 + kt);
    async16(As0 + 512, Ag1 + kt);
    async16(Bs0,       Bg0 + kt);
    async16(Bs0 + 512, Bg1 + kt);
    __syncthreads();

    bf16x8 a[4], b[4];
#pragma unroll
    for (int i = 0; i < 4; i++)
      a[i] = *(const bf16x8*)(As + (wr * 64 + i * 16 + fm) * BK + fk);
#pragma unroll
    for (int j = 0; j < 4; j++)
      b[j] = *(const bf16x8*)(Bs + (wc * 64 + j * 16 + fm) * BK + fk);
#pragma unroll
    for (int i = 0; i < 4; i++)
#pragma unroll
      for (int j = 0; j < 4; j++)
        acc[i][j] = __builtin_amdgcn_mfma_f32_16x16x32_bf16(a[i], b[j], acc[i][j], 0, 0, 0);
    __syncthreads();
  }

  const int en  = nblk + wc * 64 + (lane & 15);
  const int em0 = mblk + wr * 64 + (lane >> 4) * 4;
#pragma unroll
  for (int j = 0; j < 4; j++) {
    int col = en + j * 16;
    float bv = bias[col];
#pragma unroll
    for (int i = 0; i < 4; i++) {
#pragma unroll
      for (int r = 0; r < 4; r++) {
        int row = em0 + i * 16 + r;
        C[(size_t)row * N + col] = acc[i][j][r] + bv;
      }
    }
  }
}

// ---------------------------------------------------------------------------
// Device-scope grid barrier (fence-fence synchronization, relaxed atomics).
// All GB_ blocks co-resident (64 blocks << 256 CUs).
// ---------------------------------------------------------------------------
__device__ __forceinline__ void gbar(unsigned* bar, unsigned target) {
  __threadfence();              // release: make this block's writes agent-visible
  __syncthreads();
  if (threadIdx.x == 0) {
    __hip_atomic_fetch_add(bar, 1u, __ATOMIC_RELAXED, __HIP_MEMORY_SCOPE_AGENT);
    while (__hip_atomic_load(bar, __ATOMIC_RELAXED, __HIP_MEMORY_SCOPE_AGENT) < target)
      __builtin_amdgcn_s_sleep(2);
  }
  __syncthreads();
  __threadfence();              // acquire: invalidate so we see other blocks' writes
}

// ---------------------------------------------------------------------------
// Persistent GRU scan: all 64 timesteps in one kernel, grid barrier per step.
// Grid: 64 blocks x 256 thr. Block = (col-tile c of 16 hidden cols, all 3
// gates; batch half mh of 64 rows). Wave w owns m-tile rows m0 = mh*64+w*16.
// W_hh slice (3 gates x 16 cols x 512 K = 48 KB) lives in LDS in MFMA
// fragment order (1 KB contiguous per frag -> conflict-free ds_read_b128),
// loaded once, converted fp32->bf16 on the fly.
// h ping-pong: fp32 (exact elementwise) + bf16 (MFMA operand) copies.
// ---------------------------------------------------------------------------
__global__ __launch_bounds__(256) void gru_scan(
    const float* __restrict__ Whh_f,  // [3H][H] fp32
    const float* __restrict__ bhh,    // [3H]
    const float* __restrict__ gi,     // [M][3H] fp32
    const float* __restrict__ gf,     // [M][2H] fp32
    float* __restrict__ h0f, bf16_t* __restrict__ h0b,
    float* __restrict__ h1f, bf16_t* __restrict__ h1b,
    float* __restrict__ out,          // eo [B*T][H] ++ hT [B][H]
    unsigned* __restrict__ bar) {
  __shared__ __align__(16) bf16_t wlds[48 * 64 * 8];  // 48 frags x 1KB = 48 KB

  const int tid  = threadIdx.x;
  const int lane = tid & 63;
  const int w    = tid >> 6;
  const int lm   = lane & 15;
  const int lq   = lane >> 4;
  const int c    = blockIdx.x >> 1;   // 0..31 col-tile
  const int mh   = blockIdx.x & 1;    // 0..1  batch half
  const int n0   = c * 16;

  // ---- W_hh slice -> LDS in fragment order (once) ----
  for (int f = w; f < 48; f += 4) {
    int g = f >> 4, kt = f & 15;
    const float* src = Whh_f + (size_t)(g * H_ + n0 + lm) * H_ + kt * 32 + lq * 8;
    float4 v0 = *(const float4*)src;
    float4 v1 = *(const float4*)(src + 4);
    bf16x8 o;
    o[0] = (bf16_t)v0.x; o[1] = (bf16_t)v0.y; o[2] = (bf16_t)v0.z; o[3] = (bf16_t)v0.w;
    o[4] = (bf16_t)v1.x; o[5] = (bf16_t)v1.y; o[6] = (bf16_t)v1.z; o[7] = (bf16_t)v1.w;
    *(bf16x8*)(wlds + (f * 64 + lane) * 8) = o;
  }

  // ---- zero this block's slice of h0 (union over blocks = full h0) ----
  {
    int r  = tid >> 2;          // 0..63
    int cc = (tid & 3) * 4;     // 0,4,8,12
    int row = mh * 64 + r;
    float4 z4 = {0.f, 0.f, 0.f, 0.f};
    *(float4*)(h0f + (size_t)row * H_ + n0 + cc) = z4;
    ushort4 z2 = {0, 0, 0, 0};
    *(ushort4*)((unsigned short*)h0b + (size_t)row * H_ + n0 + cc) = z2;
  }

  const float b0 = bhh[n0 + lm];
  const float b1 = bhh[H_ + n0 + lm];
  const float b2 = bhh[2 * H_ + n0 + lm];

  const int m0 = mh * 64 + w * 16;    // wave's m-tile base row

  // elementwise inputs for step t, prefetched before the barrier spin
  float pir[4], pii[4], pin[4], pfr[4], pfi[4];
  auto prefetch = [&](int t) {
#pragma unroll
    for (int r = 0; r < 4; ++r) {
      size_t mrow = (size_t)(m0 + lq * 4 + r) * T_ + t;
      const float* gip = gi + mrow * (3 * H_) + n0 + lm;
      pir[r] = gip[0];
      pii[r] = gip[H_];
      pin[r] = gip[2 * H_];
      const float* gfp = gf + mrow * (2 * H_) + n0 + lm;
      pfr[r] = gfp[0];
      pfi[r] = gfp[H_];
    }
  };

  prefetch(0);
  unsigned tgt = GB_;
  gbar(bar, tgt);               // h0 zeroed + LDS filled, everywhere

  for (int t = 0; t < T_; ++t) {
    const bf16_t* hin_b = (t & 1) ? h1b : h0b;
    const float*  hin_f = (t & 1) ? h1f : h0f;
    bf16_t* hout_b = (t & 1) ? h0b : h1b;
    float*  hout_f = (t & 1) ? h0f : h1f;

    // A fragments: h rows m0+lm, k = kt*32 + lq*8
    const bf16_t* aRow = hin_b + (size_t)(m0 + lm) * H_ + lq * 8;
    bf16x8 a[16];
#pragma unroll
    for (int kt = 0; kt < 16; ++kt) a[kt] = *(const bf16x8*)(aRow + kt * 32);

    float hp[4];
#pragma unroll
    for (int r = 0; r < 4; ++r)
      hp[r] = hin_f[(size_t)(m0 + lq * 4 + r) * H_ + n0 + lm];

    floatx4 acc[3] = {};
#pragma unroll
    for (int g = 0; g < 3; ++g)
#pragma unroll
      for (int kt = 0; kt < 16; ++kt) {
        bf16x8 b = *(const bf16x8*)(wlds + ((g * 16 + kt) * 64 + lane) * 8);
        acc[g] = __builtin_amdgcn_mfma_f32_16x16x32_bf16(a[kt], b, acc[g], 0, 0, 0);
      }

#pragma unroll
    for (int r = 0; r < 4; ++r) {
      int brow = m0 + lq * 4 + r;
      size_t mrow = (size_t)brow * T_ + t;
      float hr = acc[0][r] + b0;
      float hi = acc[1][r] + b1;
      float hn = acc[2][r] + b2;
      float rg = 1.f / (1.f + __expf(-(pir[r] + hr + pfr[r])));
      float ig = 1.f / (1.f + __expf(-(pii[r] + hi + pfi[r])));
      float ng = tanhf(pin[r] + rg * hn);
      float hy = ng + ig * (hp[r] - ng);

      out[mrow * H_ + n0 + lm] = hy;
      hout_f[(size_t)brow * H_ + n0 + lm] = hy;
      hout_b[(size_t)brow * H_ + n0 + lm] = (bf16_t)hy;
      if (t == T_ - 1)
        out[(size_t)M_ * H_ + (size_t)brow * H_ + n0 + lm] = hy;  // hT
    }

    if (t + 1 < T_) {
      prefetch(t + 1);          // independent of h; hides HBM behind the spin
      tgt += GB_;
      gbar(bar, tgt);
    }
  }
}

// ---------------------------------------------------------------------------
extern "C" void kernel_launch(void* const* d_in, const int* in_sizes, int n_in,
                              void* d_out, int out_size, void* d_ws, size_t ws_size,
                              hipStream_t stream) {
  const float* feat0 = (const float*)d_in[0];
  const float* feat1 = (const float*)d_in[1];
  const float* W_ih  = (const float*)d_in[2];
  const float* b_ih  = (const float*)d_in[3];
  const float* W_hh  = (const float*)d_in[4];
  const float* b_hh  = (const float*)d_in[5];
  const float* W_fh  = (const float*)d_in[6];
  const float* b_fh  = (const float*)d_in[7];
  float* out = (float*)d_out;

  char* p = (char*)d_ws;
  unsigned* bar = (unsigned*)p;  p += 256;
  float*  h0f  = (float*)p;  p += (size_t)B_ * H_ * 4;
  bf16_t* h0b  = (bf16_t*)p; p += (size_t)B_ * H_ * 2;
  float*  h1f  = (float*)p;  p += (size_t)B_ * H_ * 4;
  bf16_t* h1b  = (bf16_t*)p; p += (size_t)B_ * H_ * 2;
  float*  gi   = (float*)p;  p += (size_t)M_ * 3 * H_ * 4;   // 48 MB
  float*  gf   = (float*)p;  p += (size_t)M_ * 2 * H_ * 4;   // 32 MB
  bf16_t* A1   = (bf16_t*)p; p += (size_t)M_ * IN_ * 2;      // 32 MB
  bf16_t* A0   = (bf16_t*)p; p += (size_t)M_ * FS_ * 2;      // 24 MB
  bf16_t* Wihb = (bf16_t*)p; p += (size_t)3 * H_ * IN_ * 2;  // 6 MB
  bf16_t* Wfhb = (bf16_t*)p; p += (size_t)2 * H_ * FS_ * 2;  // 3 MB

  hipMemsetAsync(bar, 0, 256, stream);   // ws is re-poisoned before every launch

  auto cvt = [&](const float* s, bf16_t* d, size_t n) {
    int n8 = (int)(n / 8);
    cvt_bf16_k<<<(n8 + 255) / 256, 256, 0, stream>>>(s, d, n8);
  };
  cvt(feat1, A1, (size_t)M_ * IN_);
  cvt(feat0, A0, (size_t)M_ * FS_);
  cvt(W_ih, Wihb, (size_t)3 * H_ * IN_);
  cvt(W_fh, Wfhb, (size_t)2 * H_ * FS_);

  // gi = feat1 @ W_ih^T + b_ih   : M=8192 N=1536 K=2048
  gemm_bt_bias<<<dim3((3 * H_) / BN, M_ / BM), 256, 0, stream>>>(
      A1, Wihb, b_ih, gi, M_, 3 * H_, IN_);
  // gf = feat0 @ W_fh^T + b_fh   : M=8192 N=1024 K=1536
  gemm_bt_bias<<<dim3((2 * H_) / BN, M_ / BM), 256, 0, stream>>>(
      A0, Wfhb, b_fh, gf, M_, 2 * H_, FS_);

  // full recurrence in one persistent kernel (64 blocks, grid barrier/step)
  gru_scan<<<GB_, 256, 0, stream>>>(W_hh, b_hh, gi, gf,
                                    h0f, h0b, h1f, h1b, out, bar);
}

// Round 3
// 728.850 us; speedup vs baseline: 1.9162x; 1.9162x over previous
//
#include <hip/hip_runtime.h>
#include <cstdint>
#include <cstddef>

typedef __bf16 bf16_t;
typedef bf16_t bf16x8 __attribute__((ext_vector_type(8)));
typedef float floatx4 __attribute__((ext_vector_type(4)));
typedef unsigned long long u64;

#define B_   128
#define T_   64
#define H_   512
#define IN_  2048
#define FS_  1536
#define M_   (B_ * T_)   // 8192
#define GB_  64          // persistent-kernel grid blocks (2 groups of 32)

// ---------------------------------------------------------------------------
// async global->LDS, 16B per lane. LDS dest is wave-uniform base + lane*16.
// ---------------------------------------------------------------------------
__device__ __forceinline__ void async16(void* lds, const void* gp) {
  __builtin_amdgcn_global_load_lds(
      (const __attribute__((address_space(1))) void*)gp,
      (__attribute__((address_space(3))) void*)lds, 16, 0, 0);
}

// ---------------------------------------------------------------------------
// Coherent (agent-scope, relaxed) loads/stores: compile to sc0/sc1-flagged
// global ops -> write-through to / read-from the cross-XCD coherence point.
// NO cache-flush fences anywhere (that was round 2's 17 us/step).
// ---------------------------------------------------------------------------
__device__ __forceinline__ u64 cload64(const u64* p) {
  return __hip_atomic_load((u64*)p, __ATOMIC_RELAXED, __HIP_MEMORY_SCOPE_AGENT);
}
__device__ __forceinline__ float cloadf(const float* p) {
  return __hip_atomic_load((float*)p, __ATOMIC_RELAXED, __HIP_MEMORY_SCOPE_AGENT);
}
__device__ __forceinline__ void cstore64(u64* p, u64 v) {
  __hip_atomic_store(p, v, __ATOMIC_RELAXED, __HIP_MEMORY_SCOPE_AGENT);
}
__device__ __forceinline__ void cstoref(float* p, float v) {
  __hip_atomic_store(p, v, __ATOMIC_RELAXED, __HIP_MEMORY_SCOPE_AGENT);
}
__device__ __forceinline__ void cstore16(unsigned short* p, unsigned short v) {
  __hip_atomic_store(p, v, __ATOMIC_RELAXED, __HIP_MEMORY_SCOPE_AGENT);
}

// ---------------------------------------------------------------------------
// fp32 -> bf16 conversion, 8 elems/thread
// ---------------------------------------------------------------------------
__global__ __launch_bounds__(256) void cvt_bf16_k(const float* __restrict__ s,
                                                  bf16_t* __restrict__ d, int n8) {
  int i = blockIdx.x * 256 + threadIdx.x;
  if (i >= n8) return;
  const float4* s4 = (const float4*)s;
  float4 v0 = s4[2 * (size_t)i];
  float4 v1 = s4[2 * (size_t)i + 1];
  bf16x8 o;
  o[0] = (bf16_t)v0.x; o[1] = (bf16_t)v0.y; o[2] = (bf16_t)v0.z; o[3] = (bf16_t)v0.w;
  o[4] = (bf16_t)v1.x; o[5] = (bf16_t)v1.y; o[6] = (bf16_t)v1.z; o[7] = (bf16_t)v1.w;
  *(bf16x8*)(d + (size_t)i * 8) = o;
}

// ---------------------------------------------------------------------------
// C[M,N] = A[M,K] * B[N,K]^T + bias[N]   (bf16 in, fp32 out) — m97 structure
// ---------------------------------------------------------------------------
#define BM 128
#define BN 128
#define BK 32

__global__ __launch_bounds__(256) void gemm_bt_bias(
    const bf16_t* __restrict__ A, const bf16_t* __restrict__ B,
    const float* __restrict__ bias, float* __restrict__ C,
    int M, int N, int K) {
  __shared__ __align__(16) bf16_t As[BM * BK];
  __shared__ __align__(16) bf16_t Bs[BN * BK];

  const int tid  = threadIdx.x;
  const int lane = tid & 63;
  const int wave = tid >> 6;
  const int wr = wave >> 1, wc = wave & 1;
  const int mblk = blockIdx.y * BM;
  const int nblk = blockIdx.x * BN;

  const int sr = lane >> 2;
  const int sc = (lane & 3) * 8;
  const int c0 = wave * 2;

  const bf16_t* Ag0 = A + (size_t)(mblk + c0 * 16 + sr) * K + sc;
  const bf16_t* Ag1 = A + (size_t)(mblk + c0 * 16 + 16 + sr) * K + sc;
  const bf16_t* Bg0 = B + (size_t)(nblk + c0 * 16 + sr) * K + sc;
  const bf16_t* Bg1 = B + (size_t)(nblk + c0 * 16 + 16 + sr) * K + sc;
  bf16_t* As0 = As + c0 * 512;
  bf16_t* Bs0 = Bs + c0 * 512;

  floatx4 acc[4][4] = {};

  const int fm = lane & 15;
  const int fk = (lane >> 4) * 8;

  for (int kt = 0; kt < K; kt += BK) {
    async16(As0,       Ag0 + kt);
    async16(As0 + 512, Ag1 + kt);
    async16(Bs0,       Bg0 + kt);
    async16(Bs0 + 512, Bg1 + kt);
    __syncthreads();

    bf16x8 a[4], b[4];
#pragma unroll
    for (int i = 0; i < 4; i++)
      a[i] = *(const bf16x8*)(As + (wr * 64 + i * 16 + fm) * BK + fk);
#pragma unroll
    for (int j = 0; j < 4; j++)
      b[j] = *(const bf16x8*)(Bs + (wc * 64 + j * 16 + fm) * BK + fk);
#pragma unroll
    for (int i = 0; i < 4; i++)
#pragma unroll
      for (int j = 0; j < 4; j++)
        acc[i][j] = __builtin_amdgcn_mfma_f32_16x16x32_bf16(a[i], b[j], acc[i][j], 0, 0, 0);
    __syncthreads();
  }

  const int en  = nblk + wc * 64 + (lane & 15);
  const int em0 = mblk + wr * 64 + (lane >> 4) * 4;
#pragma unroll
  for (int j = 0; j < 4; j++) {
    int col = en + j * 16;
    float bv = bias[col];
#pragma unroll
    for (int i = 0; i < 4; i++) {
#pragma unroll
      for (int r = 0; r < 4; r++) {
        int row = em0 + i * 16 + r;
        C[(size_t)row * N + col] = acc[i][j][r] + bv;
      }
    }
  }
}

// ---------------------------------------------------------------------------
// Group barrier: drain this wave's (coherent) stores, then relaxed counter.
// No buffer_wbl2 / buffer_inv — all cross-block data moves via sc0/sc1 ops.
// ---------------------------------------------------------------------------
__device__ __forceinline__ void gbar(unsigned* bar, unsigned target) {
  asm volatile("s_waitcnt vmcnt(0)" ::: "memory");  // stores at coherence point
  __syncthreads();                                   // whole block drained
  if (threadIdx.x == 0) {
    __hip_atomic_fetch_add(bar, 1u, __ATOMIC_RELAXED, __HIP_MEMORY_SCOPE_AGENT);
    while (__hip_atomic_load(bar, __ATOMIC_RELAXED, __HIP_MEMORY_SCOPE_AGENT) < target)
      __builtin_amdgcn_s_sleep(1);
  }
  __syncthreads();
  asm volatile("" ::: "memory");
}

// ---------------------------------------------------------------------------
// Persistent GRU scan. 64 blocks x 256 thr; block = (col-tile c: 16 hidden
// cols, all 3 gates; batch half mh: 64 rows). The two batch halves are
// independent recurrences -> two independent 32-block barrier groups.
// W_hh slice (48 KB) in LDS in MFMA-fragment order, loaded once.
// h ping-pong in fp32 + bf16; ALL h traffic via coherent atomics.
// ---------------------------------------------------------------------------
__global__ __launch_bounds__(256) void gru_scan(
    const float* __restrict__ Whh_f,  // [3H][H] fp32
    const float* __restrict__ bhh,    // [3H]
    const float* __restrict__ gi,     // [M][3H] fp32
    const float* __restrict__ gf,     // [M][2H] fp32
    float* __restrict__ h0f, bf16_t* __restrict__ h0b,
    float* __restrict__ h1f, bf16_t* __restrict__ h1b,
    float* __restrict__ out,          // eo [B*T][H] ++ hT [B][H]
    unsigned* __restrict__ bar) {     // bar[0] for mh=0 (offset 32 words for mh=1)
  __shared__ __align__(16) bf16_t wlds[48 * 64 * 8];  // 48 frags x 1KB = 48 KB

  const int tid  = threadIdx.x;
  const int lane = tid & 63;
  const int w    = tid >> 6;
  const int lm   = lane & 15;
  const int lq   = lane >> 4;
  const int c    = blockIdx.x >> 1;   // 0..31 col-tile
  const int mh   = blockIdx.x & 1;    // 0..1  batch half (independent groups)
  const int n0   = c * 16;
  unsigned* mybar = bar + mh * 32;    // separate 128B line per group

  // ---- W_hh slice -> LDS in fragment order (once) ----
  for (int f = w; f < 48; f += 4) {
    int g = f >> 4, kt = f & 15;
    const float* src = Whh_f + (size_t)(g * H_ + n0 + lm) * H_ + kt * 32 + lq * 8;
    float4 v0 = *(const float4*)src;
    float4 v1 = *(const float4*)(src + 4);
    bf16x8 o;
    o[0] = (bf16_t)v0.x; o[1] = (bf16_t)v0.y; o[2] = (bf16_t)v0.z; o[3] = (bf16_t)v0.w;
    o[4] = (bf16_t)v1.x; o[5] = (bf16_t)v1.y; o[6] = (bf16_t)v1.z; o[7] = (bf16_t)v1.w;
    *(bf16x8*)(wlds + (f * 64 + lane) * 8) = o;
  }

  // ---- zero this block's slice of h0 via coherent stores ----
  {
    int r  = tid >> 2;          // 0..63
    int cc = (tid & 3) * 4;     // 0,4,8,12
    int row = mh * 64 + r;
    u64* f64 = (u64*)(h0f + (size_t)row * H_ + n0 + cc);
    cstore64(f64, 0ull);
    cstore64(f64 + 1, 0ull);
    cstore64((u64*)((unsigned short*)h0b + (size_t)row * H_ + n0 + cc), 0ull);
  }

  const float b0 = bhh[n0 + lm];
  const float b1 = bhh[H_ + n0 + lm];
  const float b2 = bhh[2 * H_ + n0 + lm];

  const int m0 = mh * 64 + w * 16;    // wave's m-tile base row

  float pir[4], pii[4], pin[4], pfr[4], pfi[4];
  auto prefetch = [&](int t) {        // gi/gf are kernel-boundary data: cached loads
#pragma unroll
    for (int r = 0; r < 4; ++r) {
      size_t mrow = (size_t)(m0 + lq * 4 + r) * T_ + t;
      const float* gip = gi + mrow * (3 * H_) + n0 + lm;
      pir[r] = gip[0];
      pii[r] = gip[H_];
      pin[r] = gip[2 * H_];
      const float* gfp = gf + mrow * (2 * H_) + n0 + lm;
      pfr[r] = gfp[0];
      pfi[r] = gfp[H_];
    }
  };

  prefetch(0);
  unsigned tgt = 32;
  gbar(mybar, tgt);             // h0 zeroed group-wide, LDS filled

  for (int t = 0; t < T_; ++t) {
    const bf16_t* hin_b = (t & 1) ? h1b : h0b;
    const float*  hin_f = (t & 1) ? h1f : h0f;
    bf16_t* hout_b = (t & 1) ? h0b : h1b;
    float*  hout_f = (t & 1) ? h0f : h1f;

    // A fragments: h rows m0+lm, k = kt*32 + lq*8 — coherent 2x8B loads
    const u64* aRow = (const u64*)(hin_b + (size_t)(m0 + lm) * H_ + lq * 8);
    union { u64 u[2]; bf16x8 v; } a[16];
#pragma unroll
    for (int kt = 0; kt < 16; ++kt) {
      a[kt].u[0] = cload64(aRow + kt * 8);      // 32 bf16 per kt => 8 u64
      a[kt].u[1] = cload64(aRow + kt * 8 + 1);
    }

    float hp[4];
#pragma unroll
    for (int r = 0; r < 4; ++r)
      hp[r] = cloadf(hin_f + (size_t)(m0 + lq * 4 + r) * H_ + n0 + lm);

    floatx4 acc[3] = {};
#pragma unroll
    for (int g = 0; g < 3; ++g)
#pragma unroll
      for (int kt = 0; kt < 16; ++kt) {
        bf16x8 b = *(const bf16x8*)(wlds + ((g * 16 + kt) * 64 + lane) * 8);
        acc[g] = __builtin_amdgcn_mfma_f32_16x16x32_bf16(a[kt].v, b, acc[g], 0, 0, 0);
      }

#pragma unroll
    for (int r = 0; r < 4; ++r) {
      int brow = m0 + lq * 4 + r;
      size_t mrow = (size_t)brow * T_ + t;
      float hr = acc[0][r] + b0;
      float hi = acc[1][r] + b1;
      float hn = acc[2][r] + b2;
      float rg = 1.f / (1.f + __expf(-(pir[r] + hr + pfr[r])));
      float ig = 1.f / (1.f + __expf(-(pii[r] + hi + pfi[r])));
      float ng = tanhf(pin[r] + rg * hn);
      float hy = ng + ig * (hp[r] - ng);

      out[mrow * H_ + n0 + lm] = hy;                       // cached store
      cstoref(hout_f + (size_t)brow * H_ + n0 + lm, hy);   // coherent
      unsigned short hb = (unsigned short)(__builtin_bit_cast(unsigned, hy) >> 16);
      // round-to-nearest-even bf16 conversion to match (bf16_t) cast closely:
      {
        unsigned x = __builtin_bit_cast(unsigned, hy);
        unsigned lsb = (x >> 16) & 1u;
        x += 0x7fffu + lsb;
        hb = (unsigned short)(x >> 16);
      }
      cstore16((unsigned short*)hout_b + (size_t)brow * H_ + n0 + lm, hb);
      if (t == T_ - 1)
        out[(size_t)M_ * H_ + (size_t)brow * H_ + n0 + lm] = hy;  // hT
    }

    if (t + 1 < T_) {
      prefetch(t + 1);          // in flight during the barrier spin
      tgt += 32;
      gbar(mybar, tgt);
    }
  }
}

// ---------------------------------------------------------------------------
extern "C" void kernel_launch(void* const* d_in, const int* in_sizes, int n_in,
                              void* d_out, int out_size, void* d_ws, size_t ws_size,
                              hipStream_t stream) {
  const float* feat0 = (const float*)d_in[0];
  const float* feat1 = (const float*)d_in[1];
  const float* W_ih  = (const float*)d_in[2];
  const float* b_ih  = (const float*)d_in[3];
  const float* W_hh  = (const float*)d_in[4];
  const float* b_hh  = (const float*)d_in[5];
  const float* W_fh  = (const float*)d_in[6];
  const float* b_fh  = (const float*)d_in[7];
  float* out = (float*)d_out;

  char* p = (char*)d_ws;
  unsigned* bar = (unsigned*)p;  p += 256;   // two counters, 128B apart
  float*  h0f  = (float*)p;  p += (size_t)B_ * H_ * 4;
  bf16_t* h0b  = (bf16_t*)p; p += (size_t)B_ * H_ * 2;
  float*  h1f  = (float*)p;  p += (size_t)B_ * H_ * 4;
  bf16_t* h1b  = (bf16_t*)p; p += (size_t)B_ * H_ * 2;
  float*  gi   = (float*)p;  p += (size_t)M_ * 3 * H_ * 4;   // 48 MB
  float*  gf   = (float*)p;  p += (size_t)M_ * 2 * H_ * 4;   // 32 MB
  bf16_t* A1   = (bf16_t*)p; p += (size_t)M_ * IN_ * 2;      // 32 MB
  bf16_t* A0   = (bf16_t*)p; p += (size_t)M_ * FS_ * 2;      // 24 MB
  bf16_t* Wihb = (bf16_t*)p; p += (size_t)3 * H_ * IN_ * 2;  // 6 MB
  bf16_t* Wfhb = (bf16_t*)p; p += (size_t)2 * H_ * FS_ * 2;  // 3 MB

  hipMemsetAsync(bar, 0, 256, stream);

  auto cvt = [&](const float* s, bf16_t* d, size_t n) {
    int n8 = (int)(n / 8);
    cvt_bf16_k<<<(n8 + 255) / 256, 256, 0, stream>>>(s, d, n8);
  };
  cvt(feat1, A1, (size_t)M_ * IN_);
  cvt(feat0, A0, (size_t)M_ * FS_);
  cvt(W_ih, Wihb, (size_t)3 * H_ * IN_);
  cvt(W_fh, Wfhb, (size_t)2 * H_ * FS_);

  gemm_bt_bias<<<dim3((3 * H_) / BN, M_ / BM), 256, 0, stream>>>(
      A1, Wihb, b_ih, gi, M_, 3 * H_, IN_);
  gemm_bt_bias<<<dim3((2 * H_) / BN, M_ / BM), 256, 0, stream>>>(
      A0, Wfhb, b_fh, gf, M_, 2 * H_, FS_);

  gru_scan<<<GB_, 256, 0, stream>>>(W_hh, b_hh, gi, gf,
                                    h0f, h0b, h1f, h1b, out, bar);
}

// Round 4
// 549.760 us; speedup vs baseline: 2.5404x; 1.3258x over previous
//
#include <hip/hip_runtime.h>
#include <cstdint>
#include <cstddef>

typedef __bf16 bf16_t;
typedef bf16_t bf16x8 __attribute__((ext_vector_type(8)));
typedef float floatx4 __attribute__((ext_vector_type(4)));
typedef unsigned long long u64;

#define B_   128
#define T_   64
#define H_   512
#define IN_  2048
#define FS_  1536
#define M_   (B_ * T_)   // 8192
#define GB_  64

// ---------------------------------------------------------------------------
__device__ __forceinline__ void async16(void* lds, const void* gp) {
  __builtin_amdgcn_global_load_lds(
      (const __attribute__((address_space(1))) void*)gp,
      (__attribute__((address_space(3))) void*)lds, 16, 0, 0);
}

// Coherent (agent-scope relaxed) ops: sc-flagged, served at MALL (coherence
// point). No fences anywhere — the r2 flush-storm lesson.
__device__ __forceinline__ u64 cload64(const u64* p) {
  return __hip_atomic_load((u64*)p, __ATOMIC_RELAXED, __HIP_MEMORY_SCOPE_AGENT);
}
__device__ __forceinline__ void cstore64(u64* p, u64 v) {
  __hip_atomic_store(p, v, __ATOMIC_RELAXED, __HIP_MEMORY_SCOPE_AGENT);
}
__device__ __forceinline__ int cloadi(const int* p) {
  return __hip_atomic_load((int*)p, __ATOMIC_RELAXED, __HIP_MEMORY_SCOPE_AGENT);
}
__device__ __forceinline__ void cstorei(int* p, int v) {
  __hip_atomic_store(p, v, __ATOMIC_RELAXED, __HIP_MEMORY_SCOPE_AGENT);
}

__device__ __forceinline__ float fsigmoid(float x) {
  return __builtin_amdgcn_rcpf(1.f + __expf(-x));
}
__device__ __forceinline__ float ftanh(float x) {
  return 2.f * __builtin_amdgcn_rcpf(1.f + __expf(-2.f * x)) - 1.f;
}

// ---------------------------------------------------------------------------
__global__ __launch_bounds__(256) void cvt_bf16_k(const float* __restrict__ s,
                                                  bf16_t* __restrict__ d, int n8) {
  int i = blockIdx.x * 256 + threadIdx.x;
  if (i >= n8) return;
  const float4* s4 = (const float4*)s;
  float4 v0 = s4[2 * (size_t)i];
  float4 v1 = s4[2 * (size_t)i + 1];
  bf16x8 o;
  o[0] = (bf16_t)v0.x; o[1] = (bf16_t)v0.y; o[2] = (bf16_t)v0.z; o[3] = (bf16_t)v0.w;
  o[4] = (bf16_t)v1.x; o[5] = (bf16_t)v1.y; o[6] = (bf16_t)v1.z; o[7] = (bf16_t)v1.w;
  *(bf16x8*)(d + (size_t)i * 8) = o;
}

// ---------------------------------------------------------------------------
#define BM 128
#define BN 128
#define BK 32

__global__ __launch_bounds__(256) void gemm_bt_bias(
    const bf16_t* __restrict__ A, const bf16_t* __restrict__ B,
    const float* __restrict__ bias, float* __restrict__ C,
    int M, int N, int K) {
  __shared__ __align__(16) bf16_t As[BM * BK];
  __shared__ __align__(16) bf16_t Bs[BN * BK];

  const int tid  = threadIdx.x;
  const int lane = tid & 63;
  const int wave = tid >> 6;
  const int wr = wave >> 1, wc = wave & 1;
  const int mblk = blockIdx.y * BM;
  const int nblk = blockIdx.x * BN;

  const int sr = lane >> 2;
  const int sc = (lane & 3) * 8;
  const int c0 = wave * 2;

  const bf16_t* Ag0 = A + (size_t)(mblk + c0 * 16 + sr) * K + sc;
  const bf16_t* Ag1 = A + (size_t)(mblk + c0 * 16 + 16 + sr) * K + sc;
  const bf16_t* Bg0 = B + (size_t)(nblk + c0 * 16 + sr) * K + sc;
  const bf16_t* Bg1 = B + (size_t)(nblk + c0 * 16 + 16 + sr) * K + sc;
  bf16_t* As0 = As + c0 * 512;
  bf16_t* Bs0 = Bs + c0 * 512;

  floatx4 acc[4][4] = {};

  const int fm = lane & 15;
  const int fk = (lane >> 4) * 8;

  for (int kt = 0; kt < K; kt += BK) {
    async16(As0,       Ag0 + kt);
    async16(As0 + 512, Ag1 + kt);
    async16(Bs0,       Bg0 + kt);
    async16(Bs0 + 512, Bg1 + kt);
    __syncthreads();

    bf16x8 a[4], b[4];
#pragma unroll
    for (int i = 0; i < 4; i++)
      a[i] = *(const bf16x8*)(As + (wr * 64 + i * 16 + fm) * BK + fk);
#pragma unroll
    for (int j = 0; j < 4; j++)
      b[j] = *(const bf16x8*)(Bs + (wc * 64 + j * 16 + fm) * BK + fk);
#pragma unroll
    for (int i = 0; i < 4; i++)
#pragma unroll
      for (int j = 0; j < 4; j++)
        acc[i][j] = __builtin_amdgcn_mfma_f32_16x16x32_bf16(a[i], b[j], acc[i][j], 0, 0, 0);
    __syncthreads();
  }

  const int en  = nblk + wc * 64 + (lane & 15);
  const int em0 = mblk + wr * 64 + (lane >> 4) * 4;
#pragma unroll
  for (int j = 0; j < 4; j++) {
    int col = en + j * 16;
    float bv = bias[col];
#pragma unroll
    for (int i = 0; i < 4; i++) {
#pragma unroll
      for (int r = 0; r < 4; r++) {
        int row = em0 + i * 16 + r;
        C[(size_t)row * N + col] = acc[i][j][r] + bv;
      }
    }
  }
}

// ---------------------------------------------------------------------------
// Persistent GRU scan, flag-based producer/consumer (no atomics, no block
// barrier in the loop — waves fully decoupled).
//
// Grid 64 x 256. Block: ct = blockIdx.x>>1 (16 hidden cols, 3 gates),
// mh = blockIdx.x&1 (batch half, 64 rows). Wave w owns rows w*16..w*16+15.
//
// h layout (bf16, per parity): [half][ct][row(64)][col(16)] — each wave's
// publish is one contiguous 512 B block (no cross-block line sharing).
// Flags: flg[half][ct][w], 64-B stride; value F => parity (F-1)&1 holds the
// input of step F-1. Wave w needs flags of wave-row w of all 32 ct-blocks.
// h_prev (fp32) stays in registers: producer == consumer thread.
// ---------------------------------------------------------------------------
__global__ __launch_bounds__(256) void gru_scan(
    const float* __restrict__ Whh_f,  // [3H][H] fp32
    const float* __restrict__ bhh,
    const float* __restrict__ gi,     // [M][3H]
    const float* __restrict__ gf,     // [M][2H]
    bf16_t* __restrict__ hbuf,        // 2 parities x 65536 elems
    int* __restrict__ flg,            // [2][32][4] stride 16 ints
    float* __restrict__ out) {        // eo [B*T][H] ++ hT [B][H]
  __shared__ __align__(16) bf16_t wlds[48 * 64 * 8];  // 48 KB
  __shared__ __align__(16) bf16_t swp[4][256];        // 2 KB repack scratch

  const int tid  = threadIdx.x;
  const int lane = tid & 63;
  const int w    = tid >> 6;
  const int lm   = lane & 15;
  const int lq   = lane >> 4;
  const int c    = blockIdx.x >> 1;
  const int mh   = blockIdx.x & 1;
  const int n0   = c * 16;

  // ---- W_hh slice -> LDS (fragment order), once ----
  for (int f = w; f < 48; f += 4) {
    int g = f >> 4, kt = f & 15;
    const float* src = Whh_f + (size_t)(g * H_ + n0 + lm) * H_ + kt * 32 + lq * 8;
    float4 v0 = *(const float4*)src;
    float4 v1 = *(const float4*)(src + 4);
    bf16x8 o;
    o[0] = (bf16_t)v0.x; o[1] = (bf16_t)v0.y; o[2] = (bf16_t)v0.z; o[3] = (bf16_t)v0.w;
    o[4] = (bf16_t)v1.x; o[5] = (bf16_t)v1.y; o[6] = (bf16_t)v1.z; o[7] = (bf16_t)v1.w;
    *(bf16x8*)(wlds + (f * 64 + lane) * 8) = o;
  }

  // ---- zero this wave's slice of parity-0 h, publish flag=1 ----
  {
    u64* z = (u64*)(hbuf + (((size_t)mh * 32 + c) * 64 + w * 16) * 16) + lane;
    cstore64(z, 0ull);
  }
  asm volatile("s_waitcnt vmcnt(0)" ::: "memory");
  if (lane == 0) cstorei(flg + ((mh * 32 + c) * 4 + w) * 16, 1);
  __syncthreads();   // wlds ready

  const float b0 = bhh[n0 + lm];
  const float b1 = bhh[H_ + n0 + lm];
  const float b2 = bhh[2 * H_ + n0 + lm];

  const int m0 = mh * 64 + w * 16;          // global batch-row base
  float hp[4] = {0.f, 0.f, 0.f, 0.f};      // h_prev in registers

  float pir[4], pii[4], pin[4], pfr[4], pfi[4];
  auto prefetch = [&](int t) {
#pragma unroll
    for (int r = 0; r < 4; ++r) {
      size_t mrow = (size_t)(m0 + lq * 4 + r) * T_ + t;
      const float* gip = gi + mrow * (3 * H_) + n0 + lm;
      pir[r] = gip[0];
      pii[r] = gip[H_];
      pin[r] = gip[2 * H_];
      const float* gfp = gf + mrow * (2 * H_) + n0 + lm;
      pfr[r] = gfp[0];
      pfi[r] = gfp[H_];
    }
  };
  prefetch(0);

  // flag pointer for this wave's poll: lane i checks producer ct=i (i<32 dup'd)
  const int* fpoll = flg + ((mh * 32 + (lane & 31)) * 4 + w) * 16;
  int* fme = flg + ((mh * 32 + c) * 4 + w) * 16;

  // a-frag addressing: ct = 2*kt + (lq>>1), row = w*16+lm, off = (lq&1)*8
  const size_t habase = ((size_t)mh * 32 * 64 + (size_t)w * 16 + lm) * 16 + (lq & 1) * 8;
  const size_t hct    = (size_t)(lq >> 1) * 64 * 16;   // + kt*2*64*16

  for (int t = 0; t < T_; ++t) {
    // ---- wait for all 32 producers of wave-row w ----
    for (;;) {
      int f = cloadi(fpoll);
      if (__all(f >= t + 1)) break;
      __builtin_amdgcn_s_sleep(1);
    }

    // ---- load A fragments from parity t&1 ----
    const bf16_t* hpar = hbuf + (size_t)(t & 1) * 65536;
    union { u64 u[2]; bf16x8 v; } a[16];
#pragma unroll
    for (int kt = 0; kt < 16; ++kt) {
      const u64* ap = (const u64*)(hpar + habase + hct + (size_t)kt * 2048);
      a[kt].u[0] = cload64(ap);
      a[kt].u[1] = cload64(ap + 1);
    }

    floatx4 acc[3] = {};
#pragma unroll
    for (int g = 0; g < 3; ++g)
#pragma unroll
      for (int kt = 0; kt < 16; ++kt) {
        bf16x8 b = *(const bf16x8*)(wlds + ((g * 16 + kt) * 64 + lane) * 8);
        acc[g] = __builtin_amdgcn_mfma_f32_16x16x32_bf16(a[kt].v, b, acc[g], 0, 0, 0);
      }

    // ---- elementwise + eo stores; stage bf16 h into LDS for repack ----
#pragma unroll
    for (int r = 0; r < 4; ++r) {
      int brow = m0 + lq * 4 + r;
      size_t mrow = (size_t)brow * T_ + t;
      float rg = fsigmoid(pir[r] + acc[0][r] + b0 + pfr[r]);
      float ig = fsigmoid(pii[r] + acc[1][r] + b1 + pfi[r]);
      float ng = ftanh(pin[r] + rg * (acc[2][r] + b2));
      float hy = ng + ig * (hp[r] - ng);
      hp[r] = hy;

      out[mrow * H_ + n0 + lm] = hy;
      if (t == T_ - 1)
        out[(size_t)M_ * H_ + (size_t)brow * H_ + n0 + lm] = hy;
      swp[w][(lq * 4 + r) * 16 + lm] = (bf16_t)hy;
    }

    if (t + 1 < T_) {
      // ---- repack (LDS, wave-internal) -> one 8B coherent store per lane ----
      asm volatile("s_waitcnt lgkmcnt(0)" ::: "memory");
      u64 pk = *(const u64*)(&swp[w][0] + lane * 4);
      bf16_t* hnxt = hbuf + (size_t)((t + 1) & 1) * 65536;
      u64* dst = (u64*)(hnxt + (((size_t)mh * 32 + c) * 64 + w * 16) * 16) + lane;
      cstore64(dst, pk);
      // ---- publish: drain, then flag = t+2 ----
      asm volatile("s_waitcnt vmcnt(0)" ::: "memory");
      if (lane == 0) cstorei(fme, t + 2);
      // prefetch next step's gi/gf AFTER the flag (overlaps the next poll)
      prefetch(t + 1);
    }
  }
}

// ---------------------------------------------------------------------------
extern "C" void kernel_launch(void* const* d_in, const int* in_sizes, int n_in,
                              void* d_out, int out_size, void* d_ws, size_t ws_size,
                              hipStream_t stream) {
  const float* feat0 = (const float*)d_in[0];
  const float* feat1 = (const float*)d_in[1];
  const float* W_ih  = (const float*)d_in[2];
  const float* b_ih  = (const float*)d_in[3];
  const float* W_hh  = (const float*)d_in[4];
  const float* b_hh  = (const float*)d_in[5];
  const float* W_fh  = (const float*)d_in[6];
  const float* b_fh  = (const float*)d_in[7];
  float* out = (float*)d_out;

  char* p = (char*)d_ws;
  int*    flg  = (int*)p;    p += 16384;                     // 256 flags x 64B
  bf16_t* hbuf = (bf16_t*)p; p += 2 * 65536 * 2;             // 256 KB
  float*  gi   = (float*)p;  p += (size_t)M_ * 3 * H_ * 4;   // 48 MB
  float*  gf   = (float*)p;  p += (size_t)M_ * 2 * H_ * 4;   // 32 MB
  bf16_t* A1   = (bf16_t*)p; p += (size_t)M_ * IN_ * 2;      // 32 MB
  bf16_t* A0   = (bf16_t*)p; p += (size_t)M_ * FS_ * 2;      // 24 MB
  bf16_t* Wihb = (bf16_t*)p; p += (size_t)3 * H_ * IN_ * 2;  // 6 MB
  bf16_t* Wfhb = (bf16_t*)p; p += (size_t)2 * H_ * FS_ * 2;  // 3 MB

  hipMemsetAsync(flg, 0, 16384, stream);

  auto cvt = [&](const float* s, bf16_t* d, size_t n) {
    int n8 = (int)(n / 8);
    cvt_bf16_k<<<(n8 + 255) / 256, 256, 0, stream>>>(s, d, n8);
  };
  cvt(feat1, A1, (size_t)M_ * IN_);
  cvt(feat0, A0, (size_t)M_ * FS_);
  cvt(W_ih, Wihb, (size_t)3 * H_ * IN_);
  cvt(W_fh, Wfhb, (size_t)2 * H_ * FS_);

  gemm_bt_bias<<<dim3((3 * H_) / BN, M_ / BM), 256, 0, stream>>>(
      A1, Wihb, b_ih, gi, M_, 3 * H_, IN_);
  gemm_bt_bias<<<dim3((2 * H_) / BN, M_ / BM), 256, 0, stream>>>(
      A0, Wfhb, b_fh, gf, M_, 2 * H_, FS_);

  gru_scan<<<GB_, 256, 0, stream>>>(W_hh, b_hh, gi, gf, hbuf, flg, out);
}

// Round 5
// 521.453 us; speedup vs baseline: 2.6783x; 1.0543x over previous
//
#include <hip/hip_runtime.h>
#include <cstdint>
#include <cstddef>

typedef __bf16 bf16_t;
typedef bf16_t bf16x8 __attribute__((ext_vector_type(8)));
typedef float floatx4 __attribute__((ext_vector_type(4)));
typedef unsigned long long u64;

#define B_   128
#define T_   64
#define H_   512
#define IN_  2048
#define FS_  1536
#define M_   (B_ * T_)   // 8192
#define GB_  64
#define SENT (~0ull)     // 0xFF... = 4x bf16 NaN — GRU outputs can never be NaN

// ---------------------------------------------------------------------------
__device__ __forceinline__ void async16(void* lds, const void* gp) {
  __builtin_amdgcn_global_load_lds(
      (const __attribute__((address_space(1))) void*)gp,
      (__attribute__((address_space(3))) void*)lds, 16, 0, 0);
}

// Coherent (agent-scope relaxed) ops — served at the MALL coherence point.
__device__ __forceinline__ u64 cload64(const u64* p) {
  return __hip_atomic_load((u64*)p, __ATOMIC_RELAXED, __HIP_MEMORY_SCOPE_AGENT);
}
__device__ __forceinline__ void cstore64(u64* p, u64 v) {
  __hip_atomic_store(p, v, __ATOMIC_RELAXED, __HIP_MEMORY_SCOPE_AGENT);
}

__device__ __forceinline__ float fsigmoid(float x) {
  return __builtin_amdgcn_rcpf(1.f + __expf(-x));
}
__device__ __forceinline__ float ftanh(float x) {
  return 2.f * __builtin_amdgcn_rcpf(1.f + __expf(-2.f * x)) - 1.f;
}

// ---------------------------------------------------------------------------
__global__ __launch_bounds__(256) void cvt_bf16_k(const float* __restrict__ s,
                                                  bf16_t* __restrict__ d, int n8) {
  int i = blockIdx.x * 256 + threadIdx.x;
  if (i >= n8) return;
  const float4* s4 = (const float4*)s;
  float4 v0 = s4[2 * (size_t)i];
  float4 v1 = s4[2 * (size_t)i + 1];
  bf16x8 o;
  o[0] = (bf16_t)v0.x; o[1] = (bf16_t)v0.y; o[2] = (bf16_t)v0.z; o[3] = (bf16_t)v0.w;
  o[4] = (bf16_t)v1.x; o[5] = (bf16_t)v1.y; o[6] = (bf16_t)v1.z; o[7] = (bf16_t)v1.w;
  *(bf16x8*)(d + (size_t)i * 8) = o;
}

// ---------------------------------------------------------------------------
#define BM 128
#define BN 128
#define BK 32

__global__ __launch_bounds__(256) void gemm_bt_bias(
    const bf16_t* __restrict__ A, const bf16_t* __restrict__ B,
    const float* __restrict__ bias, float* __restrict__ C,
    int M, int N, int K) {
  __shared__ __align__(16) bf16_t As[BM * BK];
  __shared__ __align__(16) bf16_t Bs[BN * BK];

  const int tid  = threadIdx.x;
  const int lane = tid & 63;
  const int wave = tid >> 6;
  const int wr = wave >> 1, wc = wave & 1;
  const int mblk = blockIdx.y * BM;
  const int nblk = blockIdx.x * BN;

  const int sr = lane >> 2;
  const int sc = (lane & 3) * 8;
  const int c0 = wave * 2;

  const bf16_t* Ag0 = A + (size_t)(mblk + c0 * 16 + sr) * K + sc;
  const bf16_t* Ag1 = A + (size_t)(mblk + c0 * 16 + 16 + sr) * K + sc;
  const bf16_t* Bg0 = B + (size_t)(nblk + c0 * 16 + sr) * K + sc;
  const bf16_t* Bg1 = B + (size_t)(nblk + c0 * 16 + 16 + sr) * K + sc;
  bf16_t* As0 = As + c0 * 512;
  bf16_t* Bs0 = Bs + c0 * 512;

  floatx4 acc[4][4] = {};

  const int fm = lane & 15;
  const int fk = (lane >> 4) * 8;

  for (int kt = 0; kt < K; kt += BK) {
    async16(As0,       Ag0 + kt);
    async16(As0 + 512, Ag1 + kt);
    async16(Bs0,       Bg0 + kt);
    async16(Bs0 + 512, Bg1 + kt);
    __syncthreads();

    bf16x8 a[4], b[4];
#pragma unroll
    for (int i = 0; i < 4; i++)
      a[i] = *(const bf16x8*)(As + (wr * 64 + i * 16 + fm) * BK + fk);
#pragma unroll
    for (int j = 0; j < 4; j++)
      b[j] = *(const bf16x8*)(Bs + (wc * 64 + j * 16 + fm) * BK + fk);
#pragma unroll
    for (int i = 0; i < 4; i++)
#pragma unroll
      for (int j = 0; j < 4; j++)
        acc[i][j] = __builtin_amdgcn_mfma_f32_16x16x32_bf16(a[i], b[j], acc[i][j], 0, 0, 0);
    __syncthreads();
  }

  const int en  = nblk + wc * 64 + (lane & 15);
  const int em0 = mblk + wr * 64 + (lane >> 4) * 4;
#pragma unroll
  for (int j = 0; j < 4; j++) {
    int col = en + j * 16;
    float bv = bias[col];
#pragma unroll
    for (int i = 0; i < 4; i++) {
#pragma unroll
      for (int r = 0; r < 4; r++) {
        int row = em0 + i * 16 + r;
        C[(size_t)row * N + col] = acc[i][j][r] + bv;
      }
    }
  }
}

// ---------------------------------------------------------------------------
// Persistent GRU scan — FLAGLESS producer/consumer.
//
// Per-step h buffers: hbuf[t] (t=0..63), each [half(2)][ct(32)][row(64)][col(16)]
// bf16 = 128 KB, pre-memset to 0xFF (bf16 NaN sentinel). Producers publish
// with one 8B atomic store per lane (atomic => a u64 is either all-sentinel
// or all-data). Consumers poll the data words directly: u64 != ~0ull.
// No flags, no producer-side drains, no buffer reuse (no skew hazard).
// h_prev stays in registers (producer thread == consumer thread).
// eo stores + gi/gf prefetch issued AFTER the publish (off critical path).
// ---------------------------------------------------------------------------
__global__ __launch_bounds__(256) void gru_scan(
    const float* __restrict__ Whh_f,  // [3H][H] fp32
    const float* __restrict__ bhh,
    const float* __restrict__ gi,     // [M][3H]
    const float* __restrict__ gf,     // [M][2H]
    bf16_t* __restrict__ hbuf,        // 64 x 65536 elems (8 MB), 0xFF-init
    float* __restrict__ out) {        // eo [B*T][H] ++ hT [B][H]
  __shared__ __align__(16) bf16_t wlds[48 * 64 * 8];  // 48 KB
  __shared__ __align__(16) bf16_t swp[4][256];        // repack scratch

  const int tid  = threadIdx.x;
  const int lane = tid & 63;
  const int w    = tid >> 6;
  const int lm   = lane & 15;
  const int lq   = lane >> 4;
  const int c    = blockIdx.x >> 1;
  const int mh   = blockIdx.x & 1;
  const int n0   = c * 16;

  // ---- W_hh slice -> LDS (fragment order), once ----
  for (int f = w; f < 48; f += 4) {
    int g = f >> 4, kt = f & 15;
    const float* src = Whh_f + (size_t)(g * H_ + n0 + lm) * H_ + kt * 32 + lq * 8;
    float4 v0 = *(const float4*)src;
    float4 v1 = *(const float4*)(src + 4);
    bf16x8 o;
    o[0] = (bf16_t)v0.x; o[1] = (bf16_t)v0.y; o[2] = (bf16_t)v0.z; o[3] = (bf16_t)v0.w;
    o[4] = (bf16_t)v1.x; o[5] = (bf16_t)v1.y; o[6] = (bf16_t)v1.z; o[7] = (bf16_t)v1.w;
    *(bf16x8*)(wlds + (f * 64 + lane) * 8) = o;
  }

  // ---- publish zeros into step-0 buffer (zeros != sentinel) ----
  {
    u64* z = (u64*)(hbuf + (((size_t)mh * 32 + c) * 64 + w * 16) * 16) + lane;
    cstore64(z, 0ull);
  }
  __syncthreads();   // wlds ready

  const float b0 = bhh[n0 + lm];
  const float b1 = bhh[H_ + n0 + lm];
  const float b2 = bhh[2 * H_ + n0 + lm];

  const int m0 = mh * 64 + w * 16;
  float hp[4] = {0.f, 0.f, 0.f, 0.f};

  float pir[4], pii[4], pin[4], pfr[4], pfi[4];
  auto prefetch = [&](int t) {
#pragma unroll
    for (int r = 0; r < 4; ++r) {
      size_t mrow = (size_t)(m0 + lq * 4 + r) * T_ + t;
      const float* gip = gi + mrow * (3 * H_) + n0 + lm;
      pir[r] = gip[0];
      pii[r] = gip[H_];
      pin[r] = gip[2 * H_];
      const float* gfp = gf + mrow * (2 * H_) + n0 + lm;
      pfr[r] = gfp[0];
      pfi[r] = gfp[H_];
    }
  };
  prefetch(0);

  // a-frag addressing within a step buffer:
  //   elem = mh*32768 + ct*1024 + (w*16+lm)*16 + colin, ct = kt*2+(lq>>1),
  //   colin = (lq&1)*8
  const size_t habase = (size_t)mh * 32768 + ((size_t)w * 16 + lm) * 16 +
                        (size_t)(lq >> 1) * 1024 + (lq & 1) * 8;

  for (int t = 0; t < T_; ++t) {
    const bf16_t* hstep = hbuf + (size_t)t * 65536;
    union { u64 u[2]; bf16x8 v; } a[16];
    // ---- poll the data itself until no lane sees the NaN sentinel ----
    for (;;) {
      int ok = 1;
#pragma unroll
      for (int kt = 0; kt < 16; ++kt) {
        const u64* ap = (const u64*)(hstep + habase + (size_t)kt * 2048);
        a[kt].u[0] = cload64(ap);
        a[kt].u[1] = cload64(ap + 1);
      }
#pragma unroll
      for (int kt = 0; kt < 16; ++kt)
        ok &= (a[kt].u[0] != SENT) & (a[kt].u[1] != SENT);
      if (__all(ok)) break;
      __builtin_amdgcn_s_sleep(1);
    }

    floatx4 acc[3] = {};
#pragma unroll
    for (int g = 0; g < 3; ++g)
#pragma unroll
      for (int kt = 0; kt < 16; ++kt) {
        bf16x8 b = *(const bf16x8*)(wlds + ((g * 16 + kt) * 64 + lane) * 8);
        acc[g] = __builtin_amdgcn_mfma_f32_16x16x32_bf16(a[kt].v, b, acc[g], 0, 0, 0);
      }

    // ---- elementwise (no stores yet) ----
    float hy[4];
#pragma unroll
    for (int r = 0; r < 4; ++r) {
      float rg = fsigmoid(pir[r] + acc[0][r] + b0 + pfr[r]);
      float ig = fsigmoid(pii[r] + acc[1][r] + b1 + pfi[r]);
      float ng = ftanh(pin[r] + rg * (acc[2][r] + b2));
      hy[r] = ng + ig * (hp[r] - ng);
      hp[r] = hy[r];
      swp[w][(lq * 4 + r) * 16 + lm] = (bf16_t)hy[r];
    }

    // ---- publish ASAP: wave-internal LDS repack -> one 8B store per lane ----
    if (t + 1 < T_) {
      asm volatile("s_waitcnt lgkmcnt(0)" ::: "memory");
      u64 pk = *(const u64*)(&swp[w][0] + lane * 4);
      u64* dst = (u64*)(hbuf + (size_t)(t + 1) * 65536 +
                        (((size_t)mh * 32 + c) * 64 + w * 16) * 16) + lane;
      cstore64(dst, pk);   // no drain, no flag — consumers poll the data
    }

    // ---- off-critical-path: eo stores, hT, next prefetch ----
#pragma unroll
    for (int r = 0; r < 4; ++r) {
      int brow = m0 + lq * 4 + r;
      size_t mrow = (size_t)brow * T_ + t;
      out[mrow * H_ + n0 + lm] = hy[r];
      if (t == T_ - 1)
        out[(size_t)M_ * H_ + (size_t)brow * H_ + n0 + lm] = hy[r];
    }
    if (t + 1 < T_) prefetch(t + 1);
  }
}

// ---------------------------------------------------------------------------
extern "C" void kernel_launch(void* const* d_in, const int* in_sizes, int n_in,
                              void* d_out, int out_size, void* d_ws, size_t ws_size,
                              hipStream_t stream) {
  const float* feat0 = (const float*)d_in[0];
  const float* feat1 = (const float*)d_in[1];
  const float* W_ih  = (const float*)d_in[2];
  const float* b_ih  = (const float*)d_in[3];
  const float* W_hh  = (const float*)d_in[4];
  const float* b_hh  = (const float*)d_in[5];
  const float* W_fh  = (const float*)d_in[6];
  const float* b_fh  = (const float*)d_in[7];
  float* out = (float*)d_out;

  char* p = (char*)d_ws;
  float*  gi   = (float*)p;  p += (size_t)M_ * 3 * H_ * 4;   // 48 MB
  float*  gf   = (float*)p;  p += (size_t)M_ * 2 * H_ * 4;   // 32 MB
  bf16_t* A1   = (bf16_t*)p; p += (size_t)M_ * IN_ * 2;      // 32 MB
  bf16_t* A0   = (bf16_t*)p; p += (size_t)M_ * FS_ * 2;      // 24 MB
  bf16_t* Wihb = (bf16_t*)p; p += (size_t)3 * H_ * IN_ * 2;  // 6 MB
  bf16_t* Wfhb = (bf16_t*)p; p += (size_t)2 * H_ * FS_ * 2;  // 3 MB

  // h step-buffers alias A0 (GEMM2 has finished reading A0 by then; stream order)
  bf16_t* hbuf = A0;   // 64 steps x 128 KB = 8 MB < 24 MB

  auto cvt = [&](const float* s, bf16_t* d, size_t n) {
    int n8 = (int)(n / 8);
    cvt_bf16_k<<<(n8 + 255) / 256, 256, 0, stream>>>(s, d, n8);
  };
  cvt(feat1, A1, (size_t)M_ * IN_);
  cvt(feat0, A0, (size_t)M_ * FS_);
  cvt(W_ih, Wihb, (size_t)3 * H_ * IN_);
  cvt(W_fh, Wfhb, (size_t)2 * H_ * FS_);

  gemm_bt_bias<<<dim3((3 * H_) / BN, M_ / BM), 256, 0, stream>>>(
      A1, Wihb, b_ih, gi, M_, 3 * H_, IN_);
  gemm_bt_bias<<<dim3((2 * H_) / BN, M_ / BM), 256, 0, stream>>>(
      A0, Wfhb, b_fh, gf, M_, 2 * H_, FS_);

  // sentinel-fill the h step-buffers (after GEMM2 consumed A0)
  hipMemsetAsync(hbuf, 0xFF, (size_t)T_ * 65536 * sizeof(bf16_t), stream);

  gru_scan<<<GB_, 256, 0, stream>>>(W_hh, b_hh, gi, gf, hbuf, out);
}